// Round 12
// baseline (361.391 us; speedup 1.0000x reference)
//
#include <hip/hip_runtime.h>
#include <math.h>

typedef unsigned short ushort_t;
typedef __attribute__((ext_vector_type(8))) short bf16x8;
typedef __attribute__((ext_vector_type(4))) float f32x4;

// ---------------- constants ----------------
#define D_MODEL 768
#define N_HEADS 12
#define D_HEAD  64
#define D_MLP   3072
#define BATCH   2
#define SEQ     2048
#define ROWS    (BATCH * SEQ)          // 4096
#define LN_EPS  1e-5f
#define QKV_LD  2304                   // combined q|k|v row stride

// ---------------- bf16 helpers ----------------
__device__ __forceinline__ ushort_t f2bf(float f) {
    unsigned u = __float_as_uint(f);
    u += 0x7fffu + ((u >> 16) & 1u);   // round-to-nearest-even
    return (ushort_t)(u >> 16);
}
__device__ __forceinline__ float bf2f(ushort_t u) {
    return __uint_as_float((unsigned)u << 16);
}

#define GLD16(g, l) __builtin_amdgcn_global_load_lds( \
    (const __attribute__((address_space(1))) void*)(g), \
    (__attribute__((address_space(3))) void*)(l), 16, 0, 0)

// ---------------- LayerNorm (fp32 in -> bf16 out) ----------------
__global__ __launch_bounds__(256) void ln_kernel(const float* __restrict__ x,
                                                 const float* __restrict__ w,
                                                 const float* __restrict__ b,
                                                 ushort_t* __restrict__ y) {
    int row = blockIdx.x;
    const float* xr = x + (size_t)row * D_MODEL;
    float v[3];
    float s = 0.f, sq = 0.f;
#pragma unroll
    for (int u = 0; u < 3; ++u) {
        v[u] = xr[threadIdx.x + u * 256];
        s += v[u];
        sq += v[u] * v[u];
    }
#pragma unroll
    for (int off = 32; off >= 1; off >>= 1) {
        s  += __shfl_xor(s, off);
        sq += __shfl_xor(sq, off);
    }
    __shared__ float ss[4], ssq[4];
    int wave = threadIdx.x >> 6;
    int lane = threadIdx.x & 63;
    if (lane == 0) { ss[wave] = s; ssq[wave] = sq; }
    __syncthreads();
    s = ss[0] + ss[1] + ss[2] + ss[3];
    sq = ssq[0] + ssq[1] + ssq[2] + ssq[3];
    float mean = s * (1.0f / D_MODEL);
    float var = sq * (1.0f / D_MODEL) - mean * mean;
    float rstd = rsqrtf(var + LN_EPS);
    ushort_t* yr = y + (size_t)row * D_MODEL;
#pragma unroll
    for (int u = 0; u < 3; ++u) {
        int idx = threadIdx.x + u * 256;
        yr[idx] = f2bf((v[u] - mean) * rstd * w[idx] + b[idx]);
    }
}

// ---------------- GELU (GPT-2 'new', exp form) ----------------
__device__ __forceinline__ float gelu_new_f(float x) {
    float y2 = -1.5957691216057308f * (x + 0.044715f * x * x * x);
    return x / (1.0f + __expf(y2));
}

// ---------------- transpose tile (device fn) ----------------
__device__ __forceinline__ void do_transpose(const float* __restrict__ in, int in_ld, long in_zs,
                                             ushort_t* __restrict__ out, int out_ld, long out_zs,
                                             int bx, int by, int bz) {
    __shared__ float T[64][65];
    long ib = (long)bz * in_zs;
    long ob = (long)bz * out_zs;
    int r0 = bx * 64;
    int c0 = by * 64;
    int tr = threadIdx.x >> 4;
    int tc4 = (threadIdx.x & 15) * 4;
#pragma unroll
    for (int i = 0; i < 4; ++i) {
        int r = i * 16 + tr;
        float4 v = *reinterpret_cast<const float4*>(in + ib + (long)(r0 + r) * in_ld + c0 + tc4);
        T[r][tc4 + 0] = v.x; T[r][tc4 + 1] = v.y;
        T[r][tc4 + 2] = v.z; T[r][tc4 + 3] = v.w;
    }
    __syncthreads();
#pragma unroll
    for (int i = 0; i < 4; ++i) {
        int oc = i * 16 + tr;
        ushort4 o;
        o.x = f2bf(T[tc4 + 0][oc]);
        o.y = f2bf(T[tc4 + 1][oc]);
        o.z = f2bf(T[tc4 + 2][oc]);
        o.w = f2bf(T[tc4 + 3][oc]);
        *reinterpret_cast<ushort4*>(out + ob + (long)(c0 + oc) * out_ld + r0 + tc4) = o;
    }
}

// ---------------- fused weight prep: 6 transposes + bias concat ----------------
__global__ __launch_bounds__(256) void prep_kernel(
        const float* __restrict__ WQ, const float* __restrict__ WK,
        const float* __restrict__ WV, const float* __restrict__ WO,
        const float* __restrict__ Win, const float* __restrict__ Wout,
        const float* __restrict__ bQ, const float* __restrict__ bK,
        const float* __restrict__ bV,
        ushort_t* __restrict__ wqkvT, ushort_t* __restrict__ woT,
        ushort_t* __restrict__ winT, ushort_t* __restrict__ woutT,
        float* __restrict__ bias_cat) {
    int id = blockIdx.x;
    if (id < 432) {                       // W_Q/W_K/W_V: [12 heads][768][64] -> [2304][768]
        int j = id / 144, r = id % 144;
        const float* src = (j == 0) ? WQ : (j == 1) ? WK : WV;
        do_transpose(src, 64, 49152, wqkvT + j * 589824, 768, 49152, r % 12, 0, r / 12);
    } else if (id < 576) {                // W_O [768][768] -> [768][768]^T
        int r = id - 432;
        do_transpose(WO, 768, 0, woT, 768, 0, r % 12, r / 12, 0);
    } else if (id < 1152) {               // W_in [768][3072] -> [3072][768]
        int r = id - 576;
        do_transpose(Win, 3072, 0, winT, 768, 0, r % 12, r / 12, 0);
    } else if (id < 1728) {               // W_out [3072][768] -> [768][3072]
        int r = id - 1152;
        do_transpose(Wout, 768, 0, woutT, 3072, 0, r % 48, r / 48, 0);
    } else {                              // bias concat
        for (int i = threadIdx.x; i < 768; i += 256) {
            bias_cat[i] = bQ[i];
            bias_cat[768 + i] = bK[i];
            bias_cat[1536 + i] = bV[i];
        }
    }
}

// ---------------- bf16 MFMA GEMM, tile TM x 128 ----------------
// TM = 128: 4 waves of 64x64 (FM=4).  TM = 64: 4 waves of 32x64 (FM=2).
// MODE 0: C bf16 = acc + bias
// MODE 1: C fp32 = acc + bias + resid   (resid may alias C)
// MODE 2: C bf16 = gelu(acc + bias)
// MODE 3: C fp32 += acc                 (accumulate in place, no bias)
template <int MODE, int TM>
__global__ __launch_bounds__(256) void mfma_gemm(
        const ushort_t* __restrict__ A, int lda,
        const ushort_t* __restrict__ Bt, int ldb,
        const float* __restrict__ bias,
        const float* __restrict__ resid,
        void* __restrict__ C, int cld, int K) {
    constexpr int FM = TM / 32;          // A-frags per wave
    constexpr int AISS = TM / 32;        // A staging issues
    __shared__ char As[TM * 128];
    __shared__ char Bs[16384];
    int tid = threadIdx.x;
    int lane = tid & 63, wv = tid >> 6;
    int wr = wv >> 1, wc = wv & 1;
    int l15 = lane & 15, lhi = lane >> 4;
    int m0 = blockIdx.y * TM, n0 = blockIdx.x * 128;

    f32x4 acc[FM][4];
#pragma unroll
    for (int i = 0; i < FM; ++i)
#pragma unroll
        for (int j = 0; j < 4; ++j) acc[i][j] = (f32x4)(0.f);

    int srow[4], scol[4];
#pragma unroll
    for (int i = 0; i < 4; ++i) {
        int p = (i * 256 + tid) << 4;
        srow[i] = p >> 7;
        scol[i] = ((p & 127) ^ ((srow[i] & 7) << 4)) >> 1;
    }
    int lbase = wv << 10;

    for (int k0 = 0; k0 < K; k0 += 64) {
#pragma unroll
        for (int i = 0; i < AISS; ++i) {
            const ushort_t* ga = A + (size_t)(m0 + srow[i]) * lda + k0 + scol[i];
            GLD16(ga, As + i * 4096 + lbase);
        }
#pragma unroll
        for (int i = 0; i < 4; ++i) {
            const ushort_t* gb = Bt + (size_t)(n0 + srow[i]) * ldb + k0 + scol[i];
            GLD16(gb, Bs + i * 4096 + lbase);
        }
        __syncthreads();

        bf16x8 af[FM][2], bfr[4][2];
#pragma unroll
        for (int f = 0; f < FM; ++f)
#pragma unroll
            for (int h = 0; h < 2; ++h) {
                int ar = wr * (TM / 2) + f * 16 + l15;
                int ac = h * 64 + lhi * 16;
                af[f][h] = *reinterpret_cast<const bf16x8*>(As + ar * 128 + (ac ^ ((ar & 7) << 4)));
            }
#pragma unroll
        for (int f = 0; f < 4; ++f)
#pragma unroll
            for (int h = 0; h < 2; ++h) {
                int br = wc * 64 + f * 16 + l15;
                int ac = h * 64 + lhi * 16;
                bfr[f][h] = *reinterpret_cast<const bf16x8*>(Bs + br * 128 + (ac ^ ((br & 7) << 4)));
            }
#pragma unroll
        for (int fm = 0; fm < FM; ++fm)
#pragma unroll
            for (int fn = 0; fn < 4; ++fn) {
                acc[fm][fn] = __builtin_amdgcn_mfma_f32_16x16x32_bf16(af[fm][0], bfr[fn][0], acc[fm][fn], 0, 0, 0);
                acc[fm][fn] = __builtin_amdgcn_mfma_f32_16x16x32_bf16(af[fm][1], bfr[fn][1], acc[fm][fn], 0, 0, 0);
            }
        __syncthreads();
    }

#pragma unroll
    for (int fm = 0; fm < FM; ++fm)
#pragma unroll
        for (int fn = 0; fn < 4; ++fn)
#pragma unroll
            for (int i = 0; i < 4; ++i) {
                int m = m0 + wr * (TM / 2) + fm * 16 + lhi * 4 + i;
                int n = n0 + wc * 64 + fn * 16 + l15;
                float v = acc[fm][fn][i];
                if (MODE != 3) v += bias[n];
                if (MODE == 0) {
                    ((ushort_t*)C)[(size_t)m * cld + n] = f2bf(v);
                } else if (MODE == 1) {
                    ((float*)C)[(size_t)m * cld + n] = v + resid[(size_t)m * cld + n];
                } else if (MODE == 2) {
                    ((ushort_t*)C)[(size_t)m * cld + n] = f2bf(gelu_new_f(v));
                } else {
                    ((float*)C)[(size_t)m * cld + n] += v;
                }
            }
}

// ---------------- MFMA causal flash attention, unpaired fine grid ----------------
// grid (64, 12, 2) = 1536 blocks, 128 threads (2 waves), 32 q rows per block.
// One 32-row q-tile per block, qt = 63 - blockIdx.x (heavy first).
// 1536 blocks x 2 waves = 3072 waves = 12 waves/CU (6 blocks/CU) -> 37.5% occ
// ceiling; balance via many small heavy-first blocks (LPT-style backfill).
// z written IN-PLACE into qkv's q slot.
__global__ __launch_bounds__(128) void attn_mfma(ushort_t* __restrict__ qkv) {
    __shared__ char Ks[8192];
    __shared__ char VT[8192];
    __shared__ char Ps[4096];   // 2 waves x [16][64] bf16 (swizzled)

    int tid = threadIdx.x;
    int lane = tid & 63, wq = tid >> 6;     // wq 0..1
    int l15 = lane & 15, lhi = lane >> 4;
    int head = blockIdx.y, batch = blockIdx.z;
    size_t rowb = (size_t)batch * SEQ;
    int hcol = head * 64;

    int srow[4], scol[4];
#pragma unroll
    for (int i = 0; i < 4; ++i) {
        int p = (i * 128 + tid) << 4;
        srow[i] = p >> 7;
        scol[i] = ((p & 127) ^ ((srow[i] & 7) << 4)) >> 1;
    }
    char* myPs = Ps + wq * 2048;

    int qt = 63 - (int)blockIdx.x;          // heavy first
    int qb0 = qt * 32 + wq * 16;

    bf16x8 qf[2];
    {
        const ushort_t* qp = qkv + (rowb + qb0 + l15) * QKV_LD + hcol;
        qf[0] = *reinterpret_cast<const bf16x8*>(qp + lhi * 8);
        qf[1] = *reinterpret_cast<const bf16x8*>(qp + 32 + lhi * 8);
    }

    float mrow[4], lrow[4];
    f32x4 o[4];
#pragma unroll
    for (int i = 0; i < 4; ++i) { mrow[i] = -1e30f; lrow[i] = 0.f; o[i] = (f32x4)(0.f); }

    int ntiles = qt >> 1;             // last kv-tile index (64-key tiles)
    for (int t = 0; t <= ntiles; ++t) {
        int kt = t << 6;
        __syncthreads();
#pragma unroll
        for (int i = 0; i < 4; ++i) {
            const ushort_t* gk = qkv + (rowb + kt + srow[i]) * QKV_LD + hcol + 768 + scol[i];
            GLD16(gk, Ks + i * 2048 + (wq << 10));
        }
        {
            const ushort_t* vp = qkv + (rowb + kt + lane) * QKV_LD + hcol + 1536 + wq * 32;
#pragma unroll
            for (int u = 0; u < 4; ++u) {
                uint4 vv = *reinterpret_cast<const uint4*>(vp + u * 8);
                int d0 = wq * 32 + u * 8;
                unsigned arr[4] = {vv.x, vv.y, vv.z, vv.w};
#pragma unroll
                for (int e2 = 0; e2 < 4; ++e2) {
                    int e = e2 * 2;
                    *(ushort_t*)(VT + (d0 + e) * 128 + ((lane << 1) ^ (e << 4))) =
                        (ushort_t)(arr[e2] & 0xffff);
                    *(ushort_t*)(VT + (d0 + e + 1) * 128 + ((lane << 1) ^ ((e + 1) << 4))) =
                        (ushort_t)(arr[e2] >> 16);
                }
            }
        }
        __syncthreads();

        f32x4 s[4];
#pragma unroll
        for (int f = 0; f < 4; ++f) s[f] = (f32x4)(0.f);
#pragma unroll
        for (int h = 0; h < 2; ++h)
#pragma unroll
            for (int f = 0; f < 4; ++f) {
                int kr = f * 16 + l15;
                bf16x8 kf = *reinterpret_cast<const bf16x8*>(
                    Ks + kr * 128 + ((h * 64 + lhi * 16) ^ ((kr & 7) << 4)));
                s[f] = __builtin_amdgcn_mfma_f32_16x16x32_bf16(qf[h], kf, s[f], 0, 0, 0);
            }

        bool lastT = (t == ntiles);
#pragma unroll
        for (int i = 0; i < 4; ++i) {
            int q = qb0 + lhi * 4 + i;
            float sv[4];
#pragma unroll
            for (int f = 0; f < 4; ++f) {
                float x = s[f][i] * 0.125f;
                if (lastT && (kt + f * 16 + l15 > q)) x = -1e30f;
                sv[f] = x;
            }
            float tm = fmaxf(fmaxf(sv[0], sv[1]), fmaxf(sv[2], sv[3]));
#pragma unroll
            for (int ofs = 1; ofs <= 8; ofs <<= 1) tm = fmaxf(tm, __shfl_xor(tm, ofs));
            float mn = fmaxf(mrow[i], tm);
            float corr = __expf(mrow[i] - mn);
            mrow[i] = mn;
            float p0 = __expf(sv[0] - mn), p1 = __expf(sv[1] - mn);
            float p2 = __expf(sv[2] - mn), p3 = __expf(sv[3] - mn);
            float su = p0 + p1 + p2 + p3;
#pragma unroll
            for (int ofs = 1; ofs <= 8; ofs <<= 1) su += __shfl_xor(su, ofs);
            lrow[i] = lrow[i] * corr + su;
#pragma unroll
            for (int fn = 0; fn < 4; ++fn) o[fn][i] *= corr;
            int prow = lhi * 4 + i;
            char* pr = myPs + prow * 128;
            int sw = (prow & 7) << 4;
            *(ushort_t*)(pr + (((0 * 16 + l15) << 1) ^ sw)) = f2bf(p0);
            *(ushort_t*)(pr + (((1 * 16 + l15) << 1) ^ sw)) = f2bf(p1);
            *(ushort_t*)(pr + (((2 * 16 + l15) << 1) ^ sw)) = f2bf(p2);
            *(ushort_t*)(pr + (((3 * 16 + l15) << 1) ^ sw)) = f2bf(p3);
        }

#pragma unroll
        for (int h = 0; h < 2; ++h) {
            bf16x8 pa = *reinterpret_cast<const bf16x8*>(
                myPs + l15 * 128 + ((h * 64 + lhi * 16) ^ ((l15 & 7) << 4)));
#pragma unroll
            for (int fn = 0; fn < 4; ++fn) {
                int dr = fn * 16 + l15;
                bf16x8 vf = *reinterpret_cast<const bf16x8*>(
                    VT + dr * 128 + ((h * 64 + lhi * 16) ^ ((dr & 7) << 4)));
                o[fn] = __builtin_amdgcn_mfma_f32_16x16x32_bf16(pa, vf, o[fn], 0, 0, 0);
            }
        }
    }

    // epilogue: write z into qkv's q slot (stride QKV_LD)
#pragma unroll
    for (int i = 0; i < 4; ++i) {
        float inv = 1.0f / lrow[i];
        size_t zr = (rowb + qb0 + lhi * 4 + i) * QKV_LD + hcol;
#pragma unroll
        for (int fn = 0; fn < 4; ++fn)
            qkv[zr + fn * 16 + l15] = f2bf(o[fn][i] * inv);
    }
}

// ---------------- launch ----------------
// ws layout (ushort units), peak 33.1 MB (< 37.75 MB proven):
//   qkv   [0,         9437184)   4096x2304; q-cols become z in-place;
//                                later x_ln2 [0,3145728) + hidden [3145728,9437184)
//   winT  [9437184,  11796480)
//   woutT [11796480, 14155776)
//   wqkvT [14155776, 15925248)
//   woT   [15925248, 16515072)
//   bias_cat (fp32)  [16515072, 16519680)
extern "C" void kernel_launch(void* const* d_in, const int* in_sizes, int n_in,
                              void* d_out, int out_size, void* d_ws, size_t ws_size,
                              hipStream_t stream) {
    const float* resid_pre = (const float*)d_in[0];
    const float* W_Q  = (const float*)d_in[1];
    const float* b_Q  = (const float*)d_in[2];
    const float* W_K  = (const float*)d_in[3];
    const float* b_K  = (const float*)d_in[4];
    const float* W_V  = (const float*)d_in[5];
    const float* b_V  = (const float*)d_in[6];
    const float* W_O  = (const float*)d_in[7];
    const float* b_O  = (const float*)d_in[8];
    const float* ln1_w = (const float*)d_in[9];
    const float* ln1_b = (const float*)d_in[10];
    const float* ln2_w = (const float*)d_in[11];
    const float* ln2_b = (const float*)d_in[12];
    const float* W_in  = (const float*)d_in[13];
    const float* b_in  = (const float*)d_in[14];
    const float* W_out = (const float*)d_in[15];
    const float* b_out = (const float*)d_in[16];
    float* out = (float*)d_out;

    ushort_t* ws = (ushort_t*)d_ws;
    ushort_t* qkv    = ws;
    ushort_t* winT   = ws + 9437184;
    ushort_t* woutT  = ws + 11796480;
    ushort_t* wqkvT  = ws + 14155776;
    ushort_t* woT    = ws + 15925248;
    float*    bias_cat = (float*)(ws + 16515072);
    ushort_t* x_ln1  = (ushort_t*)d_out;          // d_out as bf16 scratch
    ushort_t* x_ln2  = ws;                        // qkv dead after W_O gemm
    ushort_t* hidden = ws + 3145728;              // 4096x1536 bf16
    float*    resid_mid = out;

    dim3 blk(256);

    // 0. all weight prep in one launch
    prep_kernel<<<1729, blk, 0, stream>>>(W_Q, W_K, W_V, W_O, W_in, W_out,
                                          b_Q, b_K, b_V,
                                          wqkvT, woT, winT, woutT, bias_cat);
    // 1. ln1 -> x_ln1 (bf16, in d_out)
    ln_kernel<<<ROWS, blk, 0, stream>>>(resid_pre, ln1_w, ln1_b, x_ln1);
    // 2. fused QKV projection (TM=128, 576 blocks)
    mfma_gemm<0, 128><<<dim3(18, 32), blk, 0, stream>>>(x_ln1, D_MODEL, wqkvT, D_MODEL,
                                                        bias_cat, nullptr, qkv, QKV_LD, D_MODEL);
    // 3. attention (z in-place), unpaired fine grid, 1536 blocks
    attn_mfma<<<dim3(64, N_HEADS, BATCH), dim3(128), 0, stream>>>(qkv);
    // 4. W_O projection + residual (TM=64, 384 blocks); A = z at stride 2304
    mfma_gemm<1, 64><<<dim3(6, 64), blk, 0, stream>>>(qkv, QKV_LD, woT, D_MODEL,
                                                      b_O, resid_pre, resid_mid, D_MODEL, D_MODEL);
    // 5. ln2 -> x_ln2
    ln_kernel<<<ROWS, blk, 0, stream>>>(resid_mid, ln2_w, ln2_b, x_ln2);
    // 6-7. MLP, hidden-dim halves, full M, TM=64 grids
    for (int b = 0; b < 2; ++b) {
        // hidden = gelu(x_ln2 @ W_in[:, b*1536:+1536])  (768 blocks)
        mfma_gemm<2, 64><<<dim3(12, 64), blk, 0, stream>>>(x_ln2, D_MODEL, winT + b * 1536 * 768, D_MODEL,
                                                           b_in + b * 1536, nullptr, hidden, 1536, D_MODEL);
        if (b == 0) {
            mfma_gemm<1, 64><<<dim3(6, 64), blk, 0, stream>>>(hidden, 1536, woutT + b * 1536, D_MLP,
                                                              b_out, out, out, D_MODEL, 1536);
        } else {
            mfma_gemm<3, 64><<<dim3(6, 64), blk, 0, stream>>>(hidden, 1536, woutT + b * 1536, D_MLP,
                                                              nullptr, nullptr, out, D_MODEL, 1536);
        }
    }
}